// Round 6
// baseline (389.938 us; speedup 1.0000x reference)
//
#include <hip/hip_runtime.h>

#define NROW  8192      // B*T
#define D_    1024
#define E_    2048
#define P2E_  4096
#define CD_   256
#define NC_   1024
#define BETA_ 0.25f
#define SPLITK 8

typedef __attribute__((ext_vector_type(8))) short short8;
typedef __attribute__((ext_vector_type(4))) float f32x4;

__device__ __forceinline__ ushort f2bf(float x) {
    union { float f; unsigned u; } v; v.f = x;
    unsigned r = (v.u + 0x7fffu + ((v.u >> 16) & 1u)) >> 16;
    return (ushort)r;
}
__device__ __forceinline__ float bf2f(ushort h) {
    union { unsigned u; float f; } v; v.u = ((unsigned)h) << 16;
    return v.f;
}
__device__ __forceinline__ void split2(float x, ushort& h, ushort& l) {
    h = f2bf(x);
    l = f2bf(x - bf2f(h));
}
__device__ __forceinline__ float gelu_tanh(float x) {
    float x3 = x * x * x;
    return 0.5f * x * (1.0f + tanhf(0.7978845608028654f * (x + 0.044715f * x3)));
}

// async global->LDS, 16B per lane
#define GLD16(gp, lp) __builtin_amdgcn_global_load_lds( \
    (const __attribute__((address_space(1))) void*)(gp), \
    (__attribute__((address_space(3))) void*)(lp), 16, 0, 0)

// ---------------------------------------------------------------------------
// Split-bf16 (3-term) MFMA GEMM, T4 counted-vmcnt depth-2 pipeline.
//   C = A @ B^T = Ah.Bh + Ah.Bl + Al.Bh  (fp32 MFMA accumulate)
// A: M x K row-major (hi/lo bf16), B: N x K row-major (hi/lo bf16).
// Tile 128x256, BK=32, 512 threads = 8 waves (2M x 4N), wave tile 64x64.
// LDS: 3-buffer ring, 48 KB/buffer (Ah 8K | Al 8K | Bh 16K | Bl 16K) = 144 KB.
// Schedule per K-tile s (buffer s%3):
//   STAGE(s+2 -> buf[(s+2)%3])  (6 global_load_lds, 16B)
//   s_waitcnt vmcnt(12)          // tile s resident (2 tiles stay in flight)
//   s_barrier                    // all waves' contributions visible
//   ds_read 16 frags; s_waitcnt lgkmcnt(0); sched_barrier
//   48 MFMA (setprio 1)
//   s_barrier                    // gates buffer reuse at s+1's STAGE
// NO vmcnt(0) drain in the main loop (T4): load window = 2 K-tiles of MFMA.
// LDS XOR swizzle on 16B slots, both-sides (pre-swizzled global src + ds_read).
// EPI 0: gelu(x + bias[n]) -> split -> Ph/Pl concat layout (GEMM1)
// EPI 1: partial fp32 -> outF[z*NROW + m][n]  (GEMM2, split-K via blockIdx.z)
// EPI 2: zeros -> outF tile; per-row argmin of (cn[n] - 2x) -> candv/candi (GEMM3)
// ---------------------------------------------------------------------------
template<int EPI>
__global__ __launch_bounds__(512, 2)
void gemm3t(const ushort* __restrict__ Ah, const ushort* __restrict__ Al,
            const ushort* __restrict__ Bh, const ushort* __restrict__ Bl,
            int K, int ksteps,
            const float* __restrict__ bias,
            float* __restrict__ outF,
            ushort* __restrict__ oPh, ushort* __restrict__ oPl,
            const float* __restrict__ cn,
            float* __restrict__ candv, int* __restrict__ candi)
{
    __shared__ alignas(16) ushort lds[3][24576];   // 144 KB
    const int t = threadIdx.x;
    const int l = t & 63;
    const int w = t >> 6;           // 0..7
    const int wm = w >> 2;          // 0..1  (M-wave)
    const int wn = w & 3;           // 0..3  (N-wave)

    // bijective XCD chunk swizzle (all grids have gridDim.x*gridDim.y % 8 == 0)
    const int nxy = gridDim.x * gridDim.y;
    const int id  = blockIdx.y * gridDim.x + blockIdx.x;
    const int swz = (id & 7) * (nxy >> 3) + (id >> 3);
    const int bx  = swz % gridDim.x;
    const int by  = swz / gridDim.x;

    const int bm = by * 128;
    const int bn = bx * 256;
    const int kstart = (EPI == 1) ? (int)blockIdx.z * (ksteps * 32) : 0;

    // staging: thread t covers row t>>2 (0..127), 16B slot t&3 of each matrix;
    // B has a second 128-row pass. LDS dest linear (t*16B); global source
    // pre-swizzled: slot' = slot ^ ((row>>1)&3)  (= (t>>3)&3 for both passes)
    const int srow = t >> 2;
    const int scol = ((t & 3) ^ ((t >> 3) & 3)) * 8;
    const ushort* gAh = Ah + (size_t)(bm + srow) * K + kstart + scol;
    const ushort* gAl = Al + (size_t)(bm + srow) * K + kstart + scol;
    const ushort* gBh = Bh + (size_t)(bn + srow) * K + kstart + scol;
    const ushort* gBl = Bl + (size_t)(bn + srow) * K + kstart + scol;
    const size_t rstep = (size_t)128 * K;
    const int d8 = t * 8;           // element dest within each region

    f32x4 acc[4][4];
#pragma unroll
    for (int i = 0; i < 4; i++)
#pragma unroll
        for (int j = 0; j < 4; j++) acc[i][j] = (f32x4)0.0f;

    // swizzled ds_read offsets: row*32 + (kq ^ ((row>>1)&3))*8 ; row>>1&3 == (lr>>1)&3
    const int kq = l >> 4, lr = l & 15;
    const int rsw = (kq ^ ((lr >> 1) & 3)) * 8;
    int aoff[4], boff[4];
#pragma unroll
    for (int i = 0; i < 4; i++) aoff[i] = (wm * 64 + i * 16 + lr) * 32 + rsw;
#pragma unroll
    for (int j = 0; j < 4; j++) boff[j] = 8192 + (wn * 64 + j * 16 + lr) * 32 + rsw;

    // regions: Ah [0,4096) Al [4096,8192) Bh [8192,16384) Bl [16384,24576)
#define STG(b) do { \
        GLD16(gAh, &lds[b][d8]); \
        GLD16(gAl, &lds[b][4096 + d8]); \
        GLD16(gBh, &lds[b][8192 + d8]);  GLD16(gBh + rstep, &lds[b][12288 + d8]); \
        GLD16(gBl, &lds[b][16384 + d8]); GLD16(gBl + rstep, &lds[b][20480 + d8]); \
        gAh += 32; gAl += 32; gBh += 32; gBl += 32; \
    } while (0)

    STG(0);
    STG(1);
    for (int s = 0; s < ksteps; ++s) {
        const int cb = s % 3;
        if (s + 2 < ksteps) STG((s + 2) % 3);
        const int rem = ksteps - 1 - s;
        if (rem >= 2)      asm volatile("s_waitcnt vmcnt(12)" ::: "memory");
        else if (rem == 1) asm volatile("s_waitcnt vmcnt(6)"  ::: "memory");
        else               asm volatile("s_waitcnt vmcnt(0)"  ::: "memory");
        __builtin_amdgcn_s_barrier();
        __builtin_amdgcn_sched_barrier(0);

        short8 fah[4], fal[4], fbh[4], fbl[4];
#pragma unroll
        for (int i = 0; i < 4; i++) {
            fah[i] = *(const short8*)&lds[cb][aoff[i]];
            fal[i] = *(const short8*)&lds[cb][4096 + aoff[i]];
        }
#pragma unroll
        for (int j = 0; j < 4; j++) {
            fbh[j] = *(const short8*)&lds[cb][boff[j]];
            fbl[j] = *(const short8*)&lds[cb][8192 + boff[j]];
        }
        asm volatile("s_waitcnt lgkmcnt(0)" ::: "memory");
        __builtin_amdgcn_sched_barrier(0);

        __builtin_amdgcn_s_setprio(1);
#pragma unroll
        for (int i = 0; i < 4; i++)
#pragma unroll
            for (int j = 0; j < 4; j++) {
                acc[i][j] = __builtin_amdgcn_mfma_f32_16x16x32_bf16(fah[i], fbh[j], acc[i][j], 0, 0, 0);
                acc[i][j] = __builtin_amdgcn_mfma_f32_16x16x32_bf16(fah[i], fbl[j], acc[i][j], 0, 0, 0);
                acc[i][j] = __builtin_amdgcn_mfma_f32_16x16x32_bf16(fal[i], fbh[j], acc[i][j], 0, 0, 0);
            }
        __builtin_amdgcn_s_setprio(0);
        __builtin_amdgcn_s_barrier();
        __builtin_amdgcn_sched_barrier(0);
    }
#undef STG

    // epilogue: C frag -> row = i*16 + (l>>4)*4 + r, col = j*16 + (l&15)
    if constexpr (EPI == 2) {
        // reduction scratch aliases dead staging LDS
        float (*redv)[4] = (float(*)[4])&lds[0][0];     // 128*4*4B = 2 KB
        int   (*redi)[4] = (int(*)[4])&lds[0][1024];    // next 2 KB
        float cnv[4];
#pragma unroll
        for (int j = 0; j < 4; j++) cnv[j] = cn[bn + wn * 64 + j * 16 + lr];
#pragma unroll
        for (int i = 0; i < 4; i++) {
            const int grow = bm + wm * 64 + i * 16 + kq * 4;
#pragma unroll
            for (int r = 0; r < 4; r++) {
                float bv = INFINITY; int bi = 0;
#pragma unroll
                for (int j = 0; j < 4; j++) {
                    float d = cnv[j] - 2.0f * acc[i][j][r];
                    int c = bn + wn * 64 + j * 16 + lr;
                    if (d < bv) { bv = d; bi = c; }
                }
#pragma unroll
                for (int m = 1; m < 16; m <<= 1) {
                    float ov = __shfl_xor(bv, m, 64);
                    int   oi = __shfl_xor(bi, m, 64);
                    if (ov < bv || (ov == bv && oi < bi)) { bv = ov; bi = oi; }
                }
                int rl = wm * 64 + i * 16 + kq * 4 + r;
                if (lr == 0) { redv[rl][wn] = bv; redi[rl][wn] = bi; }
                // zero the encodings tile (coalesced in 16-lane groups)
#pragma unroll
                for (int j = 0; j < 4; j++)
                    outF[(size_t)(grow + r) * NC_ + bn + wn * 64 + j * 16 + lr] = 0.0f;
            }
        }
        __syncthreads();
        if (t < 128) {
            float bv = redv[t][0]; int bi = redi[t][0];
#pragma unroll
            for (int k = 1; k < 4; k++) {
                float v = redv[t][k]; int x = redi[t][k];
                if (v < bv || (v == bv && x < bi)) { bv = v; bi = x; }
            }
            candv[(size_t)(bm + t) * 4 + bx] = bv;
            candi[(size_t)(bm + t) * 4 + bx] = bi;
        }
        return;
    }

#pragma unroll
    for (int i = 0; i < 4; i++) {
        const int grow = bm + wm * 64 + i * 16 + kq * 4;
#pragma unroll
        for (int j = 0; j < 4; j++) {
            const int gcol = bn + wn * 64 + j * 16 + lr;
            f32x4 a = acc[i][j];
            if constexpr (EPI == 0) {
                const float bb = bias[gcol];
#pragma unroll
                for (int r = 0; r < 4; r++) {
                    int m = grow + r;
                    float x = gelu_tanh(a[r] + bb);
                    ushort h, lo; split2(x, h, lo);
                    int pr = (m < NROW) ? m : m - NROW;
                    int pc = ((m < NROW) ? 0 : E_) + gcol;
                    oPh[(size_t)pr * P2E_ + pc] = h;
                    oPl[(size_t)pr * P2E_ + pc] = lo;
                }
            } else if constexpr (EPI == 1) {
                float* o = outF + ((size_t)NROW * blockIdx.z + grow) * CD_ + gcol;
#pragma unroll
                for (int r = 0; r < 4; r++) o[(size_t)r * CD_] = a[r];
            }
        }
    }
}

// elementwise fp32 -> (hi,lo) bf16
__global__ void split_k(const float* __restrict__ in, ushort* __restrict__ oh,
                        ushort* __restrict__ ol, int n4)
{
    int i = blockIdx.x * blockDim.x + threadIdx.x;
    int stride = gridDim.x * blockDim.x;
    for (; i < n4; i += stride) {
        float4 v = ((const float4*)in)[i];
        ushort4 h, lo;
        split2(v.x, h.x, lo.x); split2(v.y, h.y, lo.y);
        split2(v.z, h.z, lo.z); split2(v.w, h.w, lo.w);
        ((ushort4*)oh)[i] = h;
        ((ushort4*)ol)[i] = lo;
    }
}

// transpose + split: in R x C fp32 -> out C x R (hi,lo) bf16
__global__ __launch_bounds__(1024)
void tsplit_k(const float* __restrict__ in, ushort* __restrict__ oh,
              ushort* __restrict__ ol, int R, int C)
{
    __shared__ float tile[32][33];
    int c0 = blockIdx.x * 32, r0 = blockIdx.y * 32;
    int tx = threadIdx.x, ty = threadIdx.y;
    tile[ty][tx] = in[(size_t)(r0 + ty) * C + c0 + tx];
    __syncthreads();
    float x = tile[tx][ty];
    ushort h, lo; split2(x, h, lo);
    size_t o = (size_t)(c0 + ty) * R + r0 + tx;
    oh[o] = h; ol[o] = lo;
}

// sum split-K partials + bias -> latent fp32, hi/lo bf16
__global__ __launch_bounds__(256)
void combine_k(const float* __restrict__ part, const float* __restrict__ bias,
               float* __restrict__ latent, ushort* __restrict__ lh,
               ushort* __restrict__ ll)
{
    int row = blockIdx.x, t = threadIdx.x;
    float x = bias[t];
#pragma unroll
    for (int z = 0; z < SPLITK; z++) x += part[((size_t)z * NROW + row) * CD_ + t];
    latent[(size_t)row * CD_ + t] = x;
    ushort h, lo; split2(x, h, lo);
    lh[(size_t)row * CD_ + t] = h;
    ll[(size_t)row * CD_ + t] = lo;
}

__global__ __launch_bounds__(256) void row_norms(const float* __restrict__ X,
                                                 float* __restrict__ out)
{
    __shared__ float s[256];
    int n = blockIdx.x, t = threadIdx.x;
    float v = X[(size_t)n * 256 + t];
    s[t] = v * v;
    __syncthreads();
    for (int st = 128; st > 0; st >>= 1) {
        if (t < st) s[t] += s[t + st];
        __syncthreads();
    }
    if (t == 0) out[n] = s[0];
}

__global__ void zero_hist(int* hist) { hist[threadIdx.x] = 0; }

// per-row finalize: combine 4 tile candidates -> bc; set one-hot; quantize; loss parts
__global__ __launch_bounds__(256) void vq2_kernel(
    const float* __restrict__ latent, const float* __restrict__ cb,
    const float* __restrict__ candv, const int* __restrict__ candi,
    float* __restrict__ out_enc, float* __restrict__ out_q,
    float* __restrict__ out_idx, int* __restrict__ hist, float* __restrict__ lpart)
{
    __shared__ float sd[256];
    __shared__ int sbc;
    const int n = blockIdx.x, t = threadIdx.x;
    if (t == 0) {
        const float* cv = candv + (size_t)n * 4;
        const int*   ci = candi + (size_t)n * 4;
        float bv = cv[0]; int bi = ci[0];
#pragma unroll
        for (int k = 1; k < 4; k++) {
            float v = cv[k]; int x = ci[k];
            if (v < bv || (v == bv && x < bi)) { bv = v; bi = x; }
        }
        sbc = bi;
    }
    __syncthreads();
    const int bc = sbc;
    if (t == 0) out_enc[(size_t)n * NC_ + bc] = 1.0f;  // zeros written by GEMM3 epilogue

    float lv = latent[(size_t)n * CD_ + t];
    float q  = cb[(size_t)bc * CD_ + t];
    out_q[(size_t)n * CD_ + t] = lv + (q - lv);
    float diff = q - lv;
    sd[t] = diff * diff;
    __syncthreads();
    for (int st = 128; st > 0; st >>= 1) {
        if (t < st) sd[t] += sd[t + st];
        __syncthreads();
    }
    if (t == 0) {
        lpart[n] = sd[0];
        atomicAdd(&hist[bc], 1);
        out_idx[n] = (float)bc;
    }
}

__global__ __launch_bounds__(1024) void finalize_kernel(
    const float* __restrict__ lpart, const int* __restrict__ hist,
    float* __restrict__ out_loss, float* __restrict__ out_perp)
{
    __shared__ float s[1024];
    int t = threadIdx.x;
    float x = 0.0f;
    for (int i = t; i < NROW; i += 1024) x += lpart[i];
    s[t] = x;
    __syncthreads();
    for (int st = 512; st > 0; st >>= 1) {
        if (t < st) s[t] += s[t + st];
        __syncthreads();
    }
    float total = s[0];
    __syncthreads();
    float p = (float)hist[t] * (1.0f / NROW);
    s[t] = p * logf(p + 1e-10f);
    __syncthreads();
    for (int st = 512; st > 0; st >>= 1) {
        if (t < st) s[t] += s[t + st];
        __syncthreads();
    }
    if (t == 0) {
        *out_loss = BETA_ * (total / (float)((size_t)NROW * CD_));
        *out_perp = expf(-s[0]);
    }
}

extern "C" void kernel_launch(void* const* d_in, const int* in_sizes, int n_in,
                              void* d_out, int out_size, void* d_ws, size_t ws_size,
                              hipStream_t stream)
{
    const float* states      = (const float*)d_in[0];
    const float* next_states = (const float*)d_in[1];
    const float* W_s         = (const float*)d_in[2];
    const float* b_s         = (const float*)d_in[3];
    const float* W_p         = (const float*)d_in[4];
    const float* b_p         = (const float*)d_in[5];
    const float* codebook    = (const float*)d_in[6];

    float* out      = (float*)d_out;
    float* out_q    = out;
    float* out_loss = out + (size_t)NROW * CD_;
    float* out_perp = out_loss + 1;
    float* out_enc  = out_perp + 1;                  // zeroed by GEMM3 epi, 1-set by vq2
    float* out_idx  = out_enc + (size_t)NROW * NC_;

    char* ws = (char*)d_ws;
    size_t off = 0;
    auto alloc = [&](size_t bytes) { void* p = ws + off; off += (bytes + 255) & ~255ull; return p; };

    ushort* A1h  = (ushort*)alloc((size_t)2 * NROW * D_ * 2);   // 32 MiB
    ushort* A1l  = (ushort*)alloc((size_t)2 * NROW * D_ * 2);   // 32 MiB
    ushort* WsTh = (ushort*)alloc((size_t)E_ * D_ * 2);
    ushort* WsTl = (ushort*)alloc((size_t)E_ * D_ * 2);
    ushort* WpTh = (ushort*)alloc((size_t)CD_ * P2E_ * 2);
    ushort* WpTl = (ushort*)alloc((size_t)CD_ * P2E_ * 2);
    ushort* cbh  = (ushort*)alloc((size_t)NC_ * CD_ * 2);
    ushort* cbl  = (ushort*)alloc((size_t)NC_ * CD_ * 2);
    ushort* Ph   = (ushort*)alloc((size_t)NROW * P2E_ * 2);     // 64 MiB
    ushort* Pl   = (ushort*)alloc((size_t)NROW * P2E_ * 2);
    ushort* lath = (ushort*)alloc((size_t)NROW * CD_ * 2);
    ushort* latl = (ushort*)alloc((size_t)NROW * CD_ * 2);
    float*  cbn  = (float*)alloc(NC_ * 4);
    int*    hist = (int*)alloc(NC_ * 4);
    float*  lpart= (float*)alloc(NROW * 4);
    float*  candv= (float*)alloc((size_t)NROW * 4 * 4);
    int*    candi= (int*)alloc((size_t)NROW * 4 * 4);
    // aliases over dead regions (A1/WsT dead after GEMM1):
    float* lat_part = (float*)A1h;    // SPLITK*8192*256*4 = 64 MiB over A1h+A1l
    float* latent   = (float*)WsTh;   // 8 MiB over WsTh+WsTl

    // --- conversions ---
    {
        int n4 = NROW * D_ / 4;
        split_k<<<2048, 256, 0, stream>>>(states, A1h, A1l, n4);
        split_k<<<2048, 256, 0, stream>>>(next_states, A1h + (size_t)NROW * D_,
                                          A1l + (size_t)NROW * D_, n4);
    }
    tsplit_k<<<dim3(E_ / 32, D_ / 32), dim3(32, 32), 0, stream>>>(W_s, WsTh, WsTl, D_, E_);
    tsplit_k<<<dim3(CD_ / 32, P2E_ / 32), dim3(32, 32), 0, stream>>>(W_p, WpTh, WpTl, P2E_, CD_);
    split_k<<<256, 256, 0, stream>>>(codebook, cbh, cbl, NC_ * CD_ / 4);
    row_norms<<<NC_, 256, 0, stream>>>(codebook, cbn);

    // --- GEMM1: P = gelu([states;next_states] @ W_s + b_s), concat layout, split hi/lo ---
    gemm3t<0><<<dim3(E_ / 256, 2 * NROW / 128), 512, 0, stream>>>(
        A1h, A1l, WsTh, WsTl, D_, D_ / 32, b_s, nullptr, Ph, Pl, nullptr, nullptr, nullptr);

    // --- GEMM2: latent partials (split-K = 8) ---
    gemm3t<1><<<dim3(1, NROW / 128, SPLITK), 512, 0, stream>>>(
        Ph, Pl, WpTh, WpTl, P2E_, P2E_ / 32 / SPLITK, nullptr, lat_part, nullptr, nullptr,
        nullptr, nullptr, nullptr);

    // --- combine: bias + fp32 latent + hi/lo ---
    combine_k<<<NROW, 256, 0, stream>>>(lat_part, b_p, latent, lath, latl);

    // --- GEMM3: fused distance + per-tile argmin; zeros encodings region ---
    gemm3t<2><<<dim3(NC_ / 256, NROW / 128), 512, 0, stream>>>(
        lath, latl, cbh, cbl, CD_, CD_ / 32, nullptr, out_enc, nullptr, nullptr,
        cbn, candv, candi);

    // --- VQ finalize + scalars ---
    zero_hist<<<1, NC_, 0, stream>>>(hist);
    vq2_kernel<<<NROW, 256, 0, stream>>>(latent, codebook, candv, candi,
                                         out_enc, out_q, out_idx, hist, lpart);
    finalize_kernel<<<1, 1024, 0, stream>>>(lpart, hist, out_loss, out_perp);
}

// Round 7
// 361.240 us; speedup vs baseline: 1.0794x; 1.0794x over previous
//
#include <hip/hip_runtime.h>

#define NROW  8192      // B*T
#define D_    1024
#define E_    2048
#define P2E_  4096
#define CD_   256
#define NC_   1024
#define BETA_ 0.25f
#define SPLITK 8

typedef __attribute__((ext_vector_type(8))) short short8;
typedef __attribute__((ext_vector_type(4))) float f32x4;

__device__ __forceinline__ ushort f2bf(float x) {
    union { float f; unsigned u; } v; v.f = x;
    unsigned r = (v.u + 0x7fffu + ((v.u >> 16) & 1u)) >> 16;
    return (ushort)r;
}
__device__ __forceinline__ float bf2f(ushort h) {
    union { unsigned u; float f; } v; v.u = ((unsigned)h) << 16;
    return v.f;
}
__device__ __forceinline__ void split2(float x, ushort& h, ushort& l) {
    h = f2bf(x);
    l = f2bf(x - bf2f(h));
}
__device__ __forceinline__ float gelu_tanh(float x) {
    float x3 = x * x * x;
    return 0.5f * x * (1.0f + tanhf(0.7978845608028654f * (x + 0.044715f * x3)));
}

// async global->LDS, 16B per lane
#define GLD16(gp, lp) __builtin_amdgcn_global_load_lds( \
    (const __attribute__((address_space(1))) void*)(gp), \
    (__attribute__((address_space(3))) void*)(lp), 16, 0, 0)

// ---------------------------------------------------------------------------
// Split-bf16 (3-term) MFMA GEMM.  C = A @ B^T = Ah.Bh + Ah.Bl + Al.Bh (fp32 acc)
// A: M x K row-major (hi/lo bf16), B: N x K row-major (hi/lo bf16).
// Tile 128x128, BK=32, 512 threads = 8 waves (2M x 4N), wave tile 64x32.
// Light waves: acc 4x2 f32x4 (32 AGPR), A-frags read per-i in the MFMA loop.
// __launch_bounds__(512,4) caps regs at 128 -> 4 waves/SIMD (occupancy lever;
// R4/R5/R6 showed waves/CU is the controlling variable in this family).
// SINGLE-buffer schedule (R3/R5-verified):
//   iter s: ds_read frags -> barrier -> STAGE(next tile) -> MFMA (loads fly
//   under MFMAs) -> barrier (vmcnt(0) drain)
// LDS XOR swizzle on 16B slots (both-sides: pre-swizzled global src + ds_read).
// EPI 0: gelu(x + bias[n]) -> split -> Ph/Pl concat layout (GEMM1)
// EPI 1: partial fp32 -> outF[z*NROW + m][n]  (GEMM2, split-K via blockIdx.z)
// EPI 2: zeros -> outF tile; per-row argmin of (cn[n] - 2x) -> candv/candi
//        (GEMM3; reduction scratch aliases sAh/sAl, LDS stays 32 KB)
// ---------------------------------------------------------------------------
template<int EPI>
__global__ __launch_bounds__(512, 4)
void gemm_bf16x3(const ushort* __restrict__ Ah, const ushort* __restrict__ Al,
                 const ushort* __restrict__ Bh, const ushort* __restrict__ Bl,
                 int K, int ksteps,
                 const float* __restrict__ bias,
                 float* __restrict__ outF,
                 ushort* __restrict__ oPh, ushort* __restrict__ oPl,
                 const float* __restrict__ cn,
                 float* __restrict__ candv, int* __restrict__ candi)
{
    __shared__ alignas(16) ushort sAh[4096], sAl[4096], sBh[4096], sBl[4096];
    const int t = threadIdx.x;
    const int l = t & 63;
    const int w = t >> 6;           // 0..7
    const int wm = w >> 2;          // 0..1  (M-wave, 64 rows)
    const int wn = w & 3;           // 0..3  (N-wave, 32 cols)

    // bijective XCD chunk swizzle (all grids have gridDim.x*gridDim.y % 8 == 0)
    const int nxy = gridDim.x * gridDim.y;
    const int id  = blockIdx.y * gridDim.x + blockIdx.x;
    const int swz = (id & 7) * (nxy >> 3) + (id >> 3);
    const int bx  = swz % gridDim.x;
    const int by  = swz / gridDim.x;

    const int bm = by * 128;
    const int bn = bx * 128;
    const int kstart = (EPI == 1) ? (int)blockIdx.z * (ksteps * 32) : 0;

    // staging: one pass: thread t covers row t>>2 (0..127), 16B slot t&3 of
    // each matrix. LDS dest linear (t*16B); global source pre-swizzled:
    // slot' = slot ^ ((row>>1)&3) = (t&3) ^ ((t>>3)&3)
    const int srow = t >> 2;
    const int scol = ((t & 3) ^ ((t >> 3) & 3)) * 8;
    const ushort* gAh = Ah + (size_t)(bm + srow) * K + kstart + scol;
    const ushort* gAl = Al + (size_t)(bm + srow) * K + kstart + scol;
    const ushort* gBh = Bh + (size_t)(bn + srow) * K + kstart + scol;
    const ushort* gBl = Bl + (size_t)(bn + srow) * K + kstart + scol;
    const int d8 = t * 8;

    f32x4 acc[4][2];
#pragma unroll
    for (int i = 0; i < 4; i++)
#pragma unroll
        for (int j = 0; j < 2; j++) acc[i][j] = (f32x4)0.0f;

    // swizzled ds_read: row*32 + (kq ^ ((row>>1)&3))*8; (row>>1)&3 == (lr>>1)&3
    const int kq = l >> 4, lr = l & 15;
    const int rsw = (kq ^ ((lr >> 1) & 3)) * 8;
    const int abase = (wm * 64 + lr) * 32 + rsw;          // + i*16*32
    const int bbase = (wn * 32 + lr) * 32 + rsw;          // + j*16*32

#define STAGE4() do { \
        GLD16(gAh, &sAh[d8]); GLD16(gAl, &sAl[d8]); \
        GLD16(gBh, &sBh[d8]); GLD16(gBl, &sBl[d8]); \
    } while (0)

    STAGE4();                 // tile 0
    __syncthreads();          // vmcnt(0) drain: tile 0 resident

    for (int s = 0; s < ksteps; ++s) {
        short8 fbh[2], fbl[2];
#pragma unroll
        for (int j = 0; j < 2; j++) {
            fbh[j] = *(const short8*)&sBh[bbase + j * 16 * 32];
            fbl[j] = *(const short8*)&sBl[bbase + j * 16 * 32];
        }
        short8 fah[4], fal[4];
#pragma unroll
        for (int i = 0; i < 4; i++) {
            fah[i] = *(const short8*)&sAh[abase + i * 16 * 32];
            fal[i] = *(const short8*)&sAl[abase + i * 16 * 32];
        }
        __syncthreads();      // all waves done reading this tile

        if (s + 1 < ksteps) { // issue next tile's loads; they fly under MFMAs
            gAh += 32; gAl += 32; gBh += 32; gBl += 32;
            STAGE4();
        }

        __builtin_amdgcn_s_setprio(1);
#pragma unroll
        for (int i = 0; i < 4; i++) {
#pragma unroll
            for (int j = 0; j < 2; j++) {
                acc[i][j] = __builtin_amdgcn_mfma_f32_16x16x32_bf16(fah[i], fbh[j], acc[i][j], 0, 0, 0);
                acc[i][j] = __builtin_amdgcn_mfma_f32_16x16x32_bf16(fah[i], fbl[j], acc[i][j], 0, 0, 0);
                acc[i][j] = __builtin_amdgcn_mfma_f32_16x16x32_bf16(fal[i], fbh[j], acc[i][j], 0, 0, 0);
            }
        }
        __builtin_amdgcn_s_setprio(0);
        __syncthreads();      // vmcnt(0): next tile resident
    }
#undef STAGE4

    // epilogue: C frag -> row = i*16 + kq*4 + r, col = j*16 + lr (m89 layout)
    if constexpr (EPI == 2) {
        float (*redv)[4] = (float(*)[4])sAh;   // 128*4*4B = 2 KB in dead sAh
        int   (*redi)[4] = (int(*)[4])sAl;
        float cnv[2];
#pragma unroll
        for (int j = 0; j < 2; j++) cnv[j] = cn[bn + wn * 32 + j * 16 + lr];
#pragma unroll
        for (int i = 0; i < 4; i++) {
            const int grow = bm + wm * 64 + i * 16 + kq * 4;
#pragma unroll
            for (int r = 0; r < 4; r++) {
                float bv = INFINITY; int bi = 0;
#pragma unroll
                for (int j = 0; j < 2; j++) {
                    float d = cnv[j] - 2.0f * acc[i][j][r];
                    int c = bn + wn * 32 + j * 16 + lr;
                    if (d < bv) { bv = d; bi = c; }
                }
#pragma unroll
                for (int m = 1; m < 16; m <<= 1) {
                    float ov = __shfl_xor(bv, m, 64);
                    int   oi = __shfl_xor(bi, m, 64);
                    if (ov < bv || (ov == bv && oi < bi)) { bv = ov; bi = oi; }
                }
                int rl = wm * 64 + i * 16 + kq * 4 + r;
                if (lr == 0) { redv[rl][wn] = bv; redi[rl][wn] = bi; }
                // zero the encodings tile (coalesced in 16-lane groups)
#pragma unroll
                for (int j = 0; j < 2; j++)
                    outF[(size_t)(grow + r) * NC_ + bn + wn * 32 + j * 16 + lr] = 0.0f;
            }
        }
        __syncthreads();
        if (t < 128) {
            float bv = redv[t][0]; int bi = redi[t][0];
#pragma unroll
            for (int k = 1; k < 4; k++) {
                float v = redv[t][k]; int x = redi[t][k];
                if (v < bv || (v == bv && x < bi)) { bv = v; bi = x; }
            }
            candv[(size_t)(bm + t) * 8 + bx] = bv;
            candi[(size_t)(bm + t) * 8 + bx] = bi;
        }
        return;
    }

#pragma unroll
    for (int i = 0; i < 4; i++) {
        const int grow = bm + wm * 64 + i * 16 + kq * 4;
#pragma unroll
        for (int j = 0; j < 2; j++) {
            const int gcol = bn + wn * 32 + j * 16 + lr;
            f32x4 a = acc[i][j];
            if constexpr (EPI == 0) {
                const float bb = bias[gcol];
#pragma unroll
                for (int r = 0; r < 4; r++) {
                    int m = grow + r;
                    float x = gelu_tanh(a[r] + bb);
                    ushort h, lo; split2(x, h, lo);
                    int pr = (m < NROW) ? m : m - NROW;
                    int pc = ((m < NROW) ? 0 : E_) + gcol;
                    oPh[(size_t)pr * P2E_ + pc] = h;
                    oPl[(size_t)pr * P2E_ + pc] = lo;
                }
            } else if constexpr (EPI == 1) {
                float* o = outF + ((size_t)NROW * blockIdx.z + grow) * CD_ + gcol;
#pragma unroll
                for (int r = 0; r < 4; r++) o[(size_t)r * CD_] = a[r];
            }
        }
    }
}

// elementwise fp32 -> (hi,lo) bf16
__global__ void split_k(const float* __restrict__ in, ushort* __restrict__ oh,
                        ushort* __restrict__ ol, int n4)
{
    int i = blockIdx.x * blockDim.x + threadIdx.x;
    int stride = gridDim.x * blockDim.x;
    for (; i < n4; i += stride) {
        float4 v = ((const float4*)in)[i];
        ushort4 h, lo;
        split2(v.x, h.x, lo.x); split2(v.y, h.y, lo.y);
        split2(v.z, h.z, lo.z); split2(v.w, h.w, lo.w);
        ((ushort4*)oh)[i] = h;
        ((ushort4*)ol)[i] = lo;
    }
}

// transpose + split: in R x C fp32 -> out C x R (hi,lo) bf16
__global__ __launch_bounds__(1024)
void tsplit_k(const float* __restrict__ in, ushort* __restrict__ oh,
              ushort* __restrict__ ol, int R, int C)
{
    __shared__ float tile[32][33];
    int c0 = blockIdx.x * 32, r0 = blockIdx.y * 32;
    int tx = threadIdx.x, ty = threadIdx.y;
    tile[ty][tx] = in[(size_t)(r0 + ty) * C + c0 + tx];
    __syncthreads();
    float x = tile[tx][ty];
    ushort h, lo; split2(x, h, lo);
    size_t o = (size_t)(c0 + ty) * R + r0 + tx;
    oh[o] = h; ol[o] = lo;
}

// sum split-K partials + bias -> latent fp32, hi/lo bf16
__global__ __launch_bounds__(256)
void combine_k(const float* __restrict__ part, const float* __restrict__ bias,
               float* __restrict__ latent, ushort* __restrict__ lh,
               ushort* __restrict__ ll)
{
    int row = blockIdx.x, t = threadIdx.x;
    float x = bias[t];
#pragma unroll
    for (int z = 0; z < SPLITK; z++) x += part[((size_t)z * NROW + row) * CD_ + t];
    latent[(size_t)row * CD_ + t] = x;
    ushort h, lo; split2(x, h, lo);
    lh[(size_t)row * CD_ + t] = h;
    ll[(size_t)row * CD_ + t] = lo;
}

__global__ __launch_bounds__(256) void row_norms(const float* __restrict__ X,
                                                 float* __restrict__ out)
{
    __shared__ float s[256];
    int n = blockIdx.x, t = threadIdx.x;
    float v = X[(size_t)n * 256 + t];
    s[t] = v * v;
    __syncthreads();
    for (int st = 128; st > 0; st >>= 1) {
        if (t < st) s[t] += s[t + st];
        __syncthreads();
    }
    if (t == 0) out[n] = s[0];
}

__global__ void zero_hist(int* hist) { hist[threadIdx.x] = 0; }

// per-row finalize: combine 8 tile candidates -> bc; one-hot; quantize; loss parts
__global__ __launch_bounds__(256) void vq2_kernel(
    const float* __restrict__ latent, const float* __restrict__ cb,
    const float* __restrict__ candv, const int* __restrict__ candi,
    float* __restrict__ out_enc, float* __restrict__ out_q,
    float* __restrict__ out_idx, int* __restrict__ hist, float* __restrict__ lpart)
{
    __shared__ float sd[256];
    __shared__ int sbc;
    const int n = blockIdx.x, t = threadIdx.x;
    if (t == 0) {
        const float* cv = candv + (size_t)n * 8;
        const int*   ci = candi + (size_t)n * 8;
        float bv = cv[0]; int bi = ci[0];
#pragma unroll
        for (int k = 1; k < 8; k++) {
            float v = cv[k]; int x = ci[k];
            if (v < bv || (v == bv && x < bi)) { bv = v; bi = x; }
        }
        sbc = bi;
    }
    __syncthreads();
    const int bc = sbc;
    if (t == 0) out_enc[(size_t)n * NC_ + bc] = 1.0f;  // zeros by GEMM3 epilogue

    float lv = latent[(size_t)n * CD_ + t];
    float q  = cb[(size_t)bc * CD_ + t];
    out_q[(size_t)n * CD_ + t] = lv + (q - lv);
    float diff = q - lv;
    sd[t] = diff * diff;
    __syncthreads();
    for (int st = 128; st > 0; st >>= 1) {
        if (t < st) sd[t] += sd[t + st];
        __syncthreads();
    }
    if (t == 0) {
        lpart[n] = sd[0];
        atomicAdd(&hist[bc], 1);
        out_idx[n] = (float)bc;
    }
}

__global__ __launch_bounds__(1024) void finalize_kernel(
    const float* __restrict__ lpart, const int* __restrict__ hist,
    float* __restrict__ out_loss, float* __restrict__ out_perp)
{
    __shared__ float s[1024];
    int t = threadIdx.x;
    float x = 0.0f;
    for (int i = t; i < NROW; i += 1024) x += lpart[i];
    s[t] = x;
    __syncthreads();
    for (int st = 512; st > 0; st >>= 1) {
        if (t < st) s[t] += s[t + st];
        __syncthreads();
    }
    float total = s[0];
    __syncthreads();
    float p = (float)hist[t] * (1.0f / NROW);
    s[t] = p * logf(p + 1e-10f);
    __syncthreads();
    for (int st = 512; st > 0; st >>= 1) {
        if (t < st) s[t] += s[t + st];
        __syncthreads();
    }
    if (t == 0) {
        *out_loss = BETA_ * (total / (float)((size_t)NROW * CD_));
        *out_perp = expf(-s[0]);
    }
}

extern "C" void kernel_launch(void* const* d_in, const int* in_sizes, int n_in,
                              void* d_out, int out_size, void* d_ws, size_t ws_size,
                              hipStream_t stream)
{
    const float* states      = (const float*)d_in[0];
    const float* next_states = (const float*)d_in[1];
    const float* W_s         = (const float*)d_in[2];
    const float* b_s         = (const float*)d_in[3];
    const float* W_p         = (const float*)d_in[4];
    const float* b_p         = (const float*)d_in[5];
    const float* codebook    = (const float*)d_in[6];

    float* out      = (float*)d_out;
    float* out_q    = out;
    float* out_loss = out + (size_t)NROW * CD_;
    float* out_perp = out_loss + 1;
    float* out_enc  = out_perp + 1;                  // zeroed by GEMM3 epi, 1-set by vq2
    float* out_idx  = out_enc + (size_t)NROW * NC_;

    char* ws = (char*)d_ws;
    size_t off = 0;
    auto alloc = [&](size_t bytes) { void* p = ws + off; off += (bytes + 255) & ~255ull; return p; };

    ushort* A1h  = (ushort*)alloc((size_t)2 * NROW * D_ * 2);   // 32 MiB
    ushort* A1l  = (ushort*)alloc((size_t)2 * NROW * D_ * 2);   // 32 MiB
    ushort* WsTh = (ushort*)alloc((size_t)E_ * D_ * 2);
    ushort* WsTl = (ushort*)alloc((size_t)E_ * D_ * 2);
    ushort* WpTh = (ushort*)alloc((size_t)CD_ * P2E_ * 2);
    ushort* WpTl = (ushort*)alloc((size_t)CD_ * P2E_ * 2);
    ushort* cbh  = (ushort*)alloc((size_t)NC_ * CD_ * 2);
    ushort* cbl  = (ushort*)alloc((size_t)NC_ * CD_ * 2);
    ushort* Ph   = (ushort*)alloc((size_t)NROW * P2E_ * 2);     // 64 MiB
    ushort* Pl   = (ushort*)alloc((size_t)NROW * P2E_ * 2);
    ushort* lath = (ushort*)alloc((size_t)NROW * CD_ * 2);
    ushort* latl = (ushort*)alloc((size_t)NROW * CD_ * 2);
    float*  cbn  = (float*)alloc(NC_ * 4);
    int*    hist = (int*)alloc(NC_ * 4);
    float*  lpart= (float*)alloc(NROW * 4);
    float*  candv= (float*)alloc((size_t)NROW * 8 * 4);
    int*    candi= (int*)alloc((size_t)NROW * 8 * 4);
    // aliases over dead regions (A1/WsT dead after GEMM1):
    float* lat_part = (float*)A1h;    // SPLITK*8192*256*4 = 64 MiB over A1h+A1l
    float* latent   = (float*)WsTh;   // 8 MiB over WsTh+WsTl

    // --- conversions ---
    {
        int n4 = NROW * D_ / 4;
        split_k<<<2048, 256, 0, stream>>>(states, A1h, A1l, n4);
        split_k<<<2048, 256, 0, stream>>>(next_states, A1h + (size_t)NROW * D_,
                                          A1l + (size_t)NROW * D_, n4);
    }
    tsplit_k<<<dim3(E_ / 32, D_ / 32), dim3(32, 32), 0, stream>>>(W_s, WsTh, WsTl, D_, E_);
    tsplit_k<<<dim3(CD_ / 32, P2E_ / 32), dim3(32, 32), 0, stream>>>(W_p, WpTh, WpTl, P2E_, CD_);
    split_k<<<256, 256, 0, stream>>>(codebook, cbh, cbl, NC_ * CD_ / 4);
    row_norms<<<NC_, 256, 0, stream>>>(codebook, cbn);

    // --- GEMM1: P = gelu([states;next_states] @ W_s + b_s), concat layout, split hi/lo ---
    gemm_bf16x3<0><<<dim3(E_ / 128, 2 * NROW / 128), 512, 0, stream>>>(
        A1h, A1l, WsTh, WsTl, D_, D_ / 32, b_s, nullptr, Ph, Pl, nullptr, nullptr, nullptr);

    // --- GEMM2: latent partials (split-K = 8) ---
    gemm_bf16x3<1><<<dim3(CD_ / 128, NROW / 128, SPLITK), 512, 0, stream>>>(
        Ph, Pl, WpTh, WpTl, P2E_, P2E_ / 32 / SPLITK, nullptr, lat_part, nullptr, nullptr,
        nullptr, nullptr, nullptr);

    // --- combine: bias + fp32 latent + hi/lo ---
    combine_k<<<NROW, 256, 0, stream>>>(lat_part, b_p, latent, lath, latl);

    // --- GEMM3: fused distance + per-tile argmin; zeros encodings region ---
    gemm_bf16x3<2><<<dim3(NC_ / 128, NROW / 128), 512, 0, stream>>>(
        lath, latl, cbh, cbl, CD_, CD_ / 32, nullptr, out_enc, nullptr, nullptr,
        cbn, candv, candi);

    // --- VQ finalize + scalars ---
    zero_hist<<<1, NC_, 0, stream>>>(hist);
    vq2_kernel<<<NROW, 256, 0, stream>>>(latent, codebook, candv, candi,
                                         out_enc, out_q, out_idx, hist, lpart);
    finalize_kernel<<<1, 1024, 0, stream>>>(lpart, hist, out_loss, out_perp);
}